// Round 1
// baseline (770.323 us; speedup 1.0000x reference)
//
#include <hip/hip_runtime.h>
#include <hip/hip_bf16.h>
#include <math.h>

#define NN 32768
#define EE 262144
#define DM 128
#define HH 4
#define CC 128
#define HC 512
#define RD 64
#define NRELS 64
#define LEAKS 0.2f
#define LNEPS 1e-5f

typedef __hip_bfloat16 bf16;

__device__ __forceinline__ void load8(const bf16* p, float* f) {
    uint4 u = *reinterpret_cast<const uint4*>(p);
    unsigned w0 = u.x, w1 = u.y, w2 = u.z, w3 = u.w;
    f[0] = __uint_as_float((w0 & 0xffffu) << 16);
    f[1] = __uint_as_float(w0 & 0xffff0000u);
    f[2] = __uint_as_float((w1 & 0xffffu) << 16);
    f[3] = __uint_as_float(w1 & 0xffff0000u);
    f[4] = __uint_as_float((w2 & 0xffffu) << 16);
    f[5] = __uint_as_float(w2 & 0xffff0000u);
    f[6] = __uint_as_float((w3 & 0xffffu) << 16);
    f[7] = __uint_as_float(w3 & 0xffff0000u);
}

// ---------------- CSR build ----------------
__global__ void k_deg(const int* __restrict__ dst, int* __restrict__ deg) {
    int e = blockIdx.x * 256 + threadIdx.x;
    if (e < EE) atomicAdd(&deg[dst[e]], 1);
}

__global__ void k_scan(const int* __restrict__ deg, int* __restrict__ rowptr) {
    __shared__ int part[1024];
    int t = threadIdx.x;
    int base = t * 32;
    int loc[32];
    int s = 0;
#pragma unroll
    for (int i = 0; i < 32; ++i) { loc[i] = deg[base + i]; s += loc[i]; }
    part[t] = s;
    __syncthreads();
    for (int off = 1; off < 1024; off <<= 1) {
        int v = (t >= off) ? part[t - off] : 0;
        __syncthreads();
        part[t] += v;
        __syncthreads();
    }
    int run = (t > 0) ? part[t - 1] : 0;
#pragma unroll
    for (int i = 0; i < 32; ++i) { rowptr[base + i] = run; run += loc[i]; }
    if (t == 1023) rowptr[NN] = run;
}

__global__ void k_fill(const int* __restrict__ src, const int* __restrict__ dst,
                       const int* __restrict__ etype, const int* __restrict__ rowptr,
                       int* __restrict__ cursor, unsigned* __restrict__ csr) {
    int e = blockIdx.x * 256 + threadIdx.x;
    if (e < EE) {
        int d = dst[e];
        int pos = atomicAdd(&cursor[d], 1);
        csr[rowptr[d] + pos] = (unsigned)src[e] | ((unsigned)etype[e] << 16);
    }
}

// ---------------- self-loop edge attr (mean of incoming rel_emb) ----------------
__global__ void k_selfattr(const unsigned* __restrict__ csr, const int* __restrict__ rowptr,
                           const int* __restrict__ deg, const float* __restrict__ rel_emb,
                           float* __restrict__ self_attr) {
    __shared__ float relS[NRELS * RD];  // 16 KB
    int tid = threadIdx.x;
    for (int i = tid; i < NRELS * RD; i += 256) relS[i] = rel_emb[i];
    __syncthreads();
    int wave = tid >> 6, lane = tid & 63;
    int n = blockIdx.x * 4 + wave;
    int r0 = rowptr[n];
    int d = deg[n];
    float acc = 0.f;
    for (int i = 0; i < d; ++i) {
        unsigned u = csr[r0 + i];
        acc += relS[(u >> 16) * RD + lane];
    }
    float dd = (d > 0) ? (float)d : 1.0f;
    self_attr[(size_t)n * RD + lane] = acc / dd;
}

// ---------------- W_ep = rel_emb @ We[l], bf16 [64][512] ----------------
__global__ void k_wep(const float* __restrict__ rel_emb, const float* __restrict__ We,
                      bf16* __restrict__ wep) {
    int r = blockIdx.x, c = threadIdx.x;
    __shared__ float a[RD];
    if (c < RD) a[c] = rel_emb[r * RD + c];
    __syncthreads();
    float s = 0.f;
#pragma unroll 8
    for (int k = 0; k < RD; ++k) s += a[k] * We[k * HC + c];
    wep[(size_t)r * HC + c] = __float2bfloat16(s);
}

// ---------------- ep_self = self_attr @ We[l], bf16 [N][512] ----------------
__global__ void k_eps(const float* __restrict__ self_attr, const float* __restrict__ We,
                      bf16* __restrict__ eps) {
    int c = threadIdx.x;  // 0..511
    int row0 = blockIdx.x * 16;
    __shared__ float a[16][RD];  // 4 KB
    for (int i = c; i < 16 * RD; i += 512) a[i / RD][i % RD] = self_attr[(size_t)row0 * RD + i];
    __syncthreads();
    float acc[16];
#pragma unroll
    for (int r = 0; r < 16; ++r) acc[r] = 0.f;
    for (int k = 0; k < RD; ++k) {
        float w = We[k * HC + c];
#pragma unroll
        for (int r = 0; r < 16; ++r) acc[r] += a[r][k] * w;
    }
#pragma unroll
    for (int r = 0; r < 16; ++r) eps[(size_t)(row0 + r) * HC + c] = __float2bfloat16(acc[r]);
}

// ---------------- xl/xr = h @ W + b, bf16 [N][512] ----------------
__global__ void k_gemm(const float* __restrict__ A, const float* __restrict__ W,
                       const float* __restrict__ bias, bf16* __restrict__ out) {
    int c = threadIdx.x;  // 0..511
    int row0 = blockIdx.x * 16;
    __shared__ float a[16][DM];  // 8 KB
    for (int i = c; i < 16 * DM; i += 512) a[i / DM][i % DM] = A[(size_t)row0 * DM + i];
    __syncthreads();
    float acc[16];
#pragma unroll
    for (int r = 0; r < 16; ++r) acc[r] = 0.f;
    for (int k = 0; k < DM; ++k) {
        float w = W[k * HC + c];
#pragma unroll
        for (int r = 0; r < 16; ++r) acc[r] += a[r][k] * w;
    }
    float b = bias[c];
#pragma unroll
    for (int r = 0; r < 16; ++r) out[(size_t)(row0 + r) * HC + c] = __float2bfloat16(acc[r] + b);
}

// ---------------- fused per-node: logits + online softmax + aggregate +
//                  head-mean + bias + GELU + residual + LayerNorm ----------------
__global__ void k_node(const bf16* __restrict__ xl, const bf16* __restrict__ xr,
                       const bf16* __restrict__ eps, const bf16* __restrict__ wep,
                       const unsigned* __restrict__ csr, const int* __restrict__ rowptr,
                       const float* __restrict__ attL, const float* __restrict__ biasL,
                       const float* __restrict__ lngL, const float* __restrict__ lnbL,
                       const float* __restrict__ h_in, float* __restrict__ h_out) {
    int tid = threadIdx.x;
    int lane = tid & 63;
    int wave = tid >> 6;
    int n = blockIdx.x * 4 + wave;
    int head = lane >> 4;
    const int g0 = lane * 8;          // global channel in [0,512)
    const int ch0 = (lane & 15) * 8;  // channel within head, [0,128)

    float attv[8];
#pragma unroll
    for (int j = 0; j < 8; ++j) attv[j] = attL[head * CC + ch0 + j];

    float xrn[8], epn[8], xln[8];
    load8(xr + (size_t)n * HC + g0, xrn);
    load8(eps + (size_t)n * HC + g0, epn);
    load8(xl + (size_t)n * HC + g0, xln);

    // self-loop logit (per head; each 16-lane group owns one head)
    float part = 0.f;
#pragma unroll
    for (int j = 0; j < 8; ++j) {
        float v = xln[j] + xrn[j] + epn[j];
        v = (v > 0.f) ? v : LEAKS * v;
        part += v * attv[j];
    }
    part += __shfl_xor(part, 1);
    part += __shfl_xor(part, 2);
    part += __shfl_xor(part, 4);
    part += __shfl_xor(part, 8);

    float m = part;       // running max
    float denom = 1.0f;   // exp(self - m) = 1
    float acc[8];
#pragma unroll
    for (int j = 0; j < 8; ++j) acc[j] = xln[j];

    int r0 = rowptr[n], r1 = rowptr[n + 1];
    for (int i = r0; i < r1; ++i) {
        unsigned u = csr[i];
        int s = u & 0xffffu;
        int t = u >> 16;
        float xs[8], wp[8];
        load8(xl + (size_t)s * HC + g0, xs);
        load8(wep + (size_t)t * HC + g0, wp);
        float p2 = 0.f;
#pragma unroll
        for (int j = 0; j < 8; ++j) {
            float v = xs[j] + xrn[j] + wp[j];
            v = (v > 0.f) ? v : LEAKS * v;
            p2 += v * attv[j];
        }
        p2 += __shfl_xor(p2, 1);
        p2 += __shfl_xor(p2, 2);
        p2 += __shfl_xor(p2, 4);
        p2 += __shfl_xor(p2, 8);
        float mnew = fmaxf(m, p2);
        float scale = __expf(m - mnew);
        float p = __expf(p2 - mnew);
        denom = denom * scale + p;
#pragma unroll
        for (int j = 0; j < 8; ++j) acc[j] = acc[j] * scale + p * xs[j];
        m = mnew;
    }

    // alpha normalize + mean over heads
    float inv = 1.0f / (denom + 1e-16f);
    float hn[8];
    float lsum = 0.f, lsq = 0.f;
#pragma unroll
    for (int j = 0; j < 8; ++j) {
        float v = acc[j] * inv;
        v += __shfl_xor(v, 16);
        v += __shfl_xor(v, 32);
        float x = v * 0.25f + biasL[ch0 + j];
        float ge = 0.5f * x * (1.0f + erff(x * 0.70710678f));
        float hv = h_in[(size_t)n * DM + ch0 + j] + ge;
        hn[j] = hv;
        lsum += hv;
        lsq += hv * hv;
    }
    // LayerNorm stats: 16-lane group covers all 128 channels exactly once
    lsum += __shfl_xor(lsum, 1);
    lsum += __shfl_xor(lsum, 2);
    lsum += __shfl_xor(lsum, 4);
    lsum += __shfl_xor(lsum, 8);
    lsq += __shfl_xor(lsq, 1);
    lsq += __shfl_xor(lsq, 2);
    lsq += __shfl_xor(lsq, 4);
    lsq += __shfl_xor(lsq, 8);
    float mu = lsum * (1.0f / 128.f);
    float var = lsq * (1.0f / 128.f) - mu * mu;
    float rstd = rsqrtf(var + LNEPS);
    if (lane < 16) {
#pragma unroll
        for (int j = 0; j < 8; ++j) {
            h_out[(size_t)n * DM + ch0 + j] =
                (hn[j] - mu) * rstd * lngL[ch0 + j] + lnbL[ch0 + j];
        }
    }
}

extern "C" void kernel_launch(void* const* d_in, const int* in_sizes, int n_in,
                              void* d_out, int out_size, void* d_ws, size_t ws_size,
                              hipStream_t stream) {
    const float* x_flat   = (const float*)d_in[0];
    const int*   edge_idx = (const int*)d_in[1];
    const int*   edge_typ = (const int*)d_in[2];
    // d_in[3]: valid_mask_flat — all-true in this problem; where() is identity.
    const float* rel_emb  = (const float*)d_in[4];
    const float* Wl       = (const float*)d_in[5];
    const float* bl       = (const float*)d_in[6];
    const float* Wr       = (const float*)d_in[7];
    const float* br       = (const float*)d_in[8];
    const float* We       = (const float*)d_in[9];
    const float* att      = (const float*)d_in[10];
    const float* bias_o   = (const float*)d_in[11];
    const float* ln_g     = (const float*)d_in[12];
    const float* ln_b     = (const float*)d_in[13];

    const int* srcp = edge_idx;
    const int* dstp = edge_idx + EE;

    char* w = (char*)d_ws;
    auto alloc = [&](size_t bytes) -> void* {
        void* p = (void*)w;
        w += (bytes + 255) & ~(size_t)255;
        return p;
    };
    bf16*  xl        = (bf16*)alloc((size_t)NN * HC * 2);
    bf16*  xr        = (bf16*)alloc((size_t)NN * HC * 2);
    bf16*  epsb      = (bf16*)alloc((size_t)NN * HC * 2);
    float* h_mid     = (float*)alloc((size_t)NN * DM * 4);
    float* self_attr = (float*)alloc((size_t)NN * RD * 4);
    bf16*  wep       = (bf16*)alloc((size_t)NRELS * HC * 2);
    int*   deg       = (int*)alloc((size_t)NN * 4);
    int*   rowptr    = (int*)alloc((size_t)(NN + 1) * 4);
    int*   cursor    = (int*)alloc((size_t)NN * 4);
    unsigned* csr    = (unsigned*)alloc((size_t)EE * 4);

    hipMemsetAsync(deg, 0, (size_t)NN * 4, stream);
    hipMemsetAsync(cursor, 0, (size_t)NN * 4, stream);

    k_deg<<<EE / 256, 256, 0, stream>>>(dstp, deg);
    k_scan<<<1, 1024, 0, stream>>>(deg, rowptr);
    k_fill<<<EE / 256, 256, 0, stream>>>(srcp, dstp, edge_typ, rowptr, cursor, csr);
    k_selfattr<<<NN / 4, 256, 0, stream>>>(csr, rowptr, deg, rel_emb, self_attr);

    const float* h = x_flat;
    for (int l = 0; l < 2; ++l) {
        const float* WeL = We + (size_t)l * RD * HC;
        k_wep<<<NRELS, 512, 0, stream>>>(rel_emb, WeL, wep);
        k_eps<<<NN / 16, 512, 0, stream>>>(self_attr, WeL, epsb);
        k_gemm<<<NN / 16, 512, 0, stream>>>(h, Wl + (size_t)l * DM * HC, bl + (size_t)l * HC, xl);
        k_gemm<<<NN / 16, 512, 0, stream>>>(h, Wr + (size_t)l * DM * HC, br + (size_t)l * HC, xr);
        float* hout = (l == 0) ? h_mid : (float*)d_out;
        k_node<<<NN / 4, 256, 0, stream>>>(xl, xr, epsb, wep, csr, rowptr,
                                           att + (size_t)l * HH * CC,
                                           bias_o + (size_t)l * DM,
                                           ln_g + (size_t)l * DM,
                                           ln_b + (size_t)l * DM,
                                           h, hout);
        h = hout;
    }
}

// Round 2
// 470.456 us; speedup vs baseline: 1.6374x; 1.6374x over previous
//
#include <hip/hip_runtime.h>
#include <hip/hip_bf16.h>
#include <math.h>

#define NN 32768
#define EE 262144
#define DM 128
#define HH 4
#define CC 128
#define HC 512
#define RD 64
#define NRELS 64
#define LEAKS 0.2f
#define LNEPS 1e-5f

typedef __hip_bfloat16 bf16;
typedef __attribute__((ext_vector_type(8))) short short8;
typedef __attribute__((ext_vector_type(4))) float f32x4;

__device__ __forceinline__ void load8(const bf16* p, float* f) {
    uint4 u = *reinterpret_cast<const uint4*>(p);
    unsigned w0 = u.x, w1 = u.y, w2 = u.z, w3 = u.w;
    f[0] = __uint_as_float((w0 & 0xffffu) << 16);
    f[1] = __uint_as_float(w0 & 0xffff0000u);
    f[2] = __uint_as_float((w1 & 0xffffu) << 16);
    f[3] = __uint_as_float(w1 & 0xffff0000u);
    f[4] = __uint_as_float((w2 & 0xffffu) << 16);
    f[5] = __uint_as_float(w2 & 0xffff0000u);
    f[6] = __uint_as_float((w3 & 0xffffu) << 16);
    f[7] = __uint_as_float(w3 & 0xffff0000u);
}

// ---------------- CSR build ----------------
__global__ void k_deg(const int* __restrict__ dst, int* __restrict__ deg) {
    int e = blockIdx.x * 256 + threadIdx.x;
    if (e < EE) atomicAdd(&deg[dst[e]], 1);
}

__global__ void k_scan(const int* __restrict__ deg, int* __restrict__ rowptr) {
    __shared__ int part[1024];
    int t = threadIdx.x;
    int base = t * 32;
    int loc[32];
    int s = 0;
#pragma unroll
    for (int i = 0; i < 32; ++i) { loc[i] = deg[base + i]; s += loc[i]; }
    part[t] = s;
    __syncthreads();
    for (int off = 1; off < 1024; off <<= 1) {
        int v = (t >= off) ? part[t - off] : 0;
        __syncthreads();
        part[t] += v;
        __syncthreads();
    }
    int run = (t > 0) ? part[t - 1] : 0;
#pragma unroll
    for (int i = 0; i < 32; ++i) { rowptr[base + i] = run; run += loc[i]; }
    if (t == 1023) rowptr[NN] = run;
}

__global__ void k_fill(const int* __restrict__ src, const int* __restrict__ dst,
                       const int* __restrict__ etype, const int* __restrict__ rowptr,
                       int* __restrict__ cursor, unsigned* __restrict__ csr) {
    int e = blockIdx.x * 256 + threadIdx.x;
    if (e < EE) {
        int d = dst[e];
        int pos = atomicAdd(&cursor[d], 1);
        csr[rowptr[d] + pos] = (unsigned)src[e] | ((unsigned)etype[e] << 16);
    }
}

// ---------------- h f32 -> bf16 cast ----------------
__global__ void k_cast(const float* __restrict__ x, bf16* __restrict__ hb) {
    int i = blockIdx.x * 256 + threadIdx.x;   // one per 8 elements
    const float4* p = (const float4*)x;
    float4 f0 = p[i * 2], f1 = p[i * 2 + 1];
    bf16 o[8];
    o[0] = __float2bfloat16(f0.x); o[1] = __float2bfloat16(f0.y);
    o[2] = __float2bfloat16(f0.z); o[3] = __float2bfloat16(f0.w);
    o[4] = __float2bfloat16(f1.x); o[5] = __float2bfloat16(f1.y);
    o[6] = __float2bfloat16(f1.z); o[7] = __float2bfloat16(f1.w);
    *reinterpret_cast<uint4*>(hb + (size_t)i * 8) = *reinterpret_cast<uint4*>(o);
}

// ---------------- Wt = [Wl|Wr]^T  bf16 [1024][128] ----------------
__global__ void k_repack(const float* __restrict__ Wl, const float* __restrict__ Wr,
                         bf16* __restrict__ Wt) {
    int idx = blockIdx.x * 256 + threadIdx.x;   // 131072 total
    int k = idx >> 10;
    int c = idx & 1023;
    float v = (c < HC) ? Wl[k * HC + c] : Wr[k * HC + (c - HC)];
    Wt[(size_t)c * DM + k] = __float2bfloat16(v);
}

// ---------------- wep = rel_emb @ We[l], bf16 [64][512] ----------------
__global__ void k_wep(const float* __restrict__ rel_emb, const float* __restrict__ We,
                      bf16* __restrict__ wep) {
    int r = blockIdx.x, c = threadIdx.x;
    __shared__ float a[RD];
    if (c < RD) a[c] = rel_emb[r * RD + c];
    __syncthreads();
    float s = 0.f;
#pragma unroll 8
    for (int k = 0; k < RD; ++k) s += a[k] * We[k * HC + c];
    wep[(size_t)r * HC + c] = __float2bfloat16(s);
}

// ---------------- MFMA GEMM: [xl|xr] = hb @ Wt^T + bias ----------------
// hb: bf16 [NN][128] row-major. Wt: bf16 [1024][128] row-major (= W^T).
// Per wave: 32 rows x 64 cols, K=128 in 4 steps of 32 (mfma_f32_16x16x32_bf16).
__global__ __launch_bounds__(256) void k_gemm_mfma(
    const bf16* __restrict__ hb, const bf16* __restrict__ Wt,
    const float* __restrict__ bl, const float* __restrict__ br,
    bf16* __restrict__ xlb, bf16* __restrict__ xrb) {
    int lane = threadIdx.x & 63;
    int wave = threadIdx.x >> 6;
    int rbase = blockIdx.x * 32;
    int cbase = blockIdx.y * 256 + wave * 64;
    int lr = lane & 15;
    int lk = lane >> 4;
    const short* ha = (const short*)hb;
    const short* wa = (const short*)Wt;

    short8 a[2][4], b[4][4];
#pragma unroll
    for (int mi = 0; mi < 2; ++mi)
#pragma unroll
        for (int kk = 0; kk < 4; ++kk)
            a[mi][kk] = *(const short8*)(ha + (size_t)(rbase + mi * 16 + lr) * DM + kk * 32 + lk * 8);
#pragma unroll
    for (int ni = 0; ni < 4; ++ni)
#pragma unroll
        for (int kk = 0; kk < 4; ++kk)
            b[ni][kk] = *(const short8*)(wa + (size_t)(cbase + ni * 16 + lr) * DM + kk * 32 + lk * 8);

    f32x4 c[2][4];
#pragma unroll
    for (int mi = 0; mi < 2; ++mi)
#pragma unroll
        for (int ni = 0; ni < 4; ++ni)
            c[mi][ni] = (f32x4){0.f, 0.f, 0.f, 0.f};

#pragma unroll
    for (int kk = 0; kk < 4; ++kk)
#pragma unroll
        for (int mi = 0; mi < 2; ++mi)
#pragma unroll
            for (int ni = 0; ni < 4; ++ni)
                c[mi][ni] = __builtin_amdgcn_mfma_f32_16x16x32_bf16(
                    a[mi][kk], b[ni][kk], c[mi][ni], 0, 0, 0);

#pragma unroll
    for (int ni = 0; ni < 4; ++ni) {
        int col = cbase + ni * 16 + lr;
        float bv = (col < HC) ? bl[col] : br[col - HC];
        bf16* outp;
        int cc;
        if (col < HC) { outp = xlb; cc = col; } else { outp = xrb; cc = col - HC; }
#pragma unroll
        for (int mi = 0; mi < 2; ++mi) {
#pragma unroll
            for (int r = 0; r < 4; ++r) {
                int row = rbase + mi * 16 + lk * 4 + r;
                outp[(size_t)row * HC + cc] = __float2bfloat16(c[mi][ni][r] + bv);
            }
        }
    }
}

// ---------------- fused per-node: edge loop (online softmax + wep-mean) +
//                  self-loop + head-mean + bias + GELU + residual + LN ----------------
__global__ void k_node(const bf16* __restrict__ xlb, const bf16* __restrict__ xrb,
                       const bf16* __restrict__ wep,
                       const unsigned* __restrict__ csr, const int* __restrict__ rowptr,
                       const float* __restrict__ attL, const float* __restrict__ biasL,
                       const float* __restrict__ lngL, const float* __restrict__ lnbL,
                       const float* __restrict__ h_in, float* __restrict__ h_out,
                       bf16* __restrict__ hb_out) {
    int tid = threadIdx.x;
    int lane = tid & 63;
    int wave = tid >> 6;
    int n = blockIdx.x * 4 + wave;
    int head = lane >> 4;
    const int g0 = lane * 8;          // global channel in [0,512)
    const int ch0 = (lane & 15) * 8;  // channel within head, [0,128)

    float attv[8];
#pragma unroll
    for (int j = 0; j < 8; ++j) attv[j] = attL[head * CC + ch0 + j];

    float xrn[8], xln[8];
    load8(xrb + (size_t)n * HC + g0, xrn);
    load8(xlb + (size_t)n * HC + g0, xln);

    float m = -1e30f;
    float denom = 0.f;
    float acc[8], wpsum[8];
#pragma unroll
    for (int j = 0; j < 8; ++j) { acc[j] = 0.f; wpsum[j] = 0.f; }

    int r0 = rowptr[n], r1 = rowptr[n + 1];
    int d = r1 - r0;
    for (int i = r0; i < r1; ++i) {
        unsigned u = csr[i];
        int s = u & 0xffffu;
        int t = u >> 16;
        float xs[8], wp[8];
        load8(xlb + (size_t)s * HC + g0, xs);
        load8(wep + (size_t)t * HC + g0, wp);
        float p2 = 0.f;
#pragma unroll
        for (int j = 0; j < 8; ++j) {
            wpsum[j] += wp[j];
            float v = xs[j] + xrn[j] + wp[j];
            v = (v > 0.f) ? v : LEAKS * v;
            p2 += v * attv[j];
        }
        p2 += __shfl_xor(p2, 1);
        p2 += __shfl_xor(p2, 2);
        p2 += __shfl_xor(p2, 4);
        p2 += __shfl_xor(p2, 8);
        float mnew = fmaxf(m, p2);
        float scale = __expf(m - mnew);
        float p = __expf(p2 - mnew);
        denom = denom * scale + p;
#pragma unroll
        for (int j = 0; j < 8; ++j) acc[j] = acc[j] * scale + p * xs[j];
        m = mnew;
    }

    // self-loop: ep_self = mean of incoming wep rows (linearity of @We)
    float invd = (d > 0) ? (1.0f / (float)d) : 1.0f;
    float p2 = 0.f;
#pragma unroll
    for (int j = 0; j < 8; ++j) {
        float v = xln[j] + xrn[j] + wpsum[j] * invd;
        v = (v > 0.f) ? v : LEAKS * v;
        p2 += v * attv[j];
    }
    p2 += __shfl_xor(p2, 1);
    p2 += __shfl_xor(p2, 2);
    p2 += __shfl_xor(p2, 4);
    p2 += __shfl_xor(p2, 8);
    {
        float mnew = fmaxf(m, p2);
        float scale = __expf(m - mnew);
        float p = __expf(p2 - mnew);
        denom = denom * scale + p;
#pragma unroll
        for (int j = 0; j < 8; ++j) acc[j] = acc[j] * scale + p * xln[j];
    }

    // alpha normalize + mean over heads
    float inv = 1.0f / (denom + 1e-16f);
    float hn[8];
    float lsum = 0.f, lsq = 0.f;
#pragma unroll
    for (int j = 0; j < 8; ++j) {
        float v = acc[j] * inv;
        v += __shfl_xor(v, 16);
        v += __shfl_xor(v, 32);
        float x = v * 0.25f + biasL[ch0 + j];
        float ge = 0.5f * x * (1.0f + erff(x * 0.70710678f));
        float hv = h_in[(size_t)n * DM + ch0 + j] + ge;
        hn[j] = hv;
        lsum += hv;
        lsq += hv * hv;
    }
    lsum += __shfl_xor(lsum, 1);
    lsum += __shfl_xor(lsum, 2);
    lsum += __shfl_xor(lsum, 4);
    lsum += __shfl_xor(lsum, 8);
    lsq += __shfl_xor(lsq, 1);
    lsq += __shfl_xor(lsq, 2);
    lsq += __shfl_xor(lsq, 4);
    lsq += __shfl_xor(lsq, 8);
    float mu = lsum * (1.0f / 128.f);
    float var = lsq * (1.0f / 128.f) - mu * mu;
    float rstd = rsqrtf(var + LNEPS);
    if (lane < 16) {
#pragma unroll
        for (int j = 0; j < 8; ++j) {
            float o = (hn[j] - mu) * rstd * lngL[ch0 + j] + lnbL[ch0 + j];
            h_out[(size_t)n * DM + ch0 + j] = o;
            hb_out[(size_t)n * DM + ch0 + j] = __float2bfloat16(o);
        }
    }
}

extern "C" void kernel_launch(void* const* d_in, const int* in_sizes, int n_in,
                              void* d_out, int out_size, void* d_ws, size_t ws_size,
                              hipStream_t stream) {
    const float* x_flat   = (const float*)d_in[0];
    const int*   edge_idx = (const int*)d_in[1];
    const int*   edge_typ = (const int*)d_in[2];
    // d_in[3]: valid_mask_flat — all-true; where() is identity.
    const float* rel_emb  = (const float*)d_in[4];
    const float* Wl       = (const float*)d_in[5];
    const float* bl       = (const float*)d_in[6];
    const float* Wr       = (const float*)d_in[7];
    const float* br       = (const float*)d_in[8];
    const float* We       = (const float*)d_in[9];
    const float* att      = (const float*)d_in[10];
    const float* bias_o   = (const float*)d_in[11];
    const float* ln_g     = (const float*)d_in[12];
    const float* ln_b     = (const float*)d_in[13];

    const int* srcp = edge_idx;
    const int* dstp = edge_idx + EE;

    char* w = (char*)d_ws;
    auto alloc = [&](size_t bytes) -> void* {
        void* p = (void*)w;
        w += (bytes + 255) & ~(size_t)255;
        return p;
    };
    bf16*  xlb    = (bf16*)alloc((size_t)NN * HC * 2);
    bf16*  xrb    = (bf16*)alloc((size_t)NN * HC * 2);
    bf16*  hb     = (bf16*)alloc((size_t)NN * DM * 2);
    float* h_mid  = (float*)alloc((size_t)NN * DM * 4);
    bf16*  wep    = (bf16*)alloc((size_t)NRELS * HC * 2);
    bf16*  Wt     = (bf16*)alloc((size_t)1024 * DM * 2);
    int*   deg    = (int*)alloc((size_t)NN * 4);
    int*   rowptr = (int*)alloc((size_t)(NN + 1) * 4);
    int*   cursor = (int*)alloc((size_t)NN * 4);
    unsigned* csr = (unsigned*)alloc((size_t)EE * 4);

    hipMemsetAsync(deg, 0, (size_t)NN * 4, stream);
    hipMemsetAsync(cursor, 0, (size_t)NN * 4, stream);

    k_deg<<<EE / 256, 256, 0, stream>>>(dstp, deg);
    k_scan<<<1, 1024, 0, stream>>>(deg, rowptr);
    k_fill<<<EE / 256, 256, 0, stream>>>(srcp, dstp, edge_typ, rowptr, cursor, csr);
    k_cast<<<NN * DM / 8 / 256, 256, 0, stream>>>(x_flat, hb);

    const float* h = x_flat;
    for (int l = 0; l < 2; ++l) {
        const float* WeL = We + (size_t)l * RD * HC;
        k_wep<<<NRELS, 512, 0, stream>>>(rel_emb, WeL, wep);
        k_repack<<<512, 256, 0, stream>>>(Wl + (size_t)l * DM * HC, Wr + (size_t)l * DM * HC, Wt);
        k_gemm_mfma<<<dim3(NN / 32, 4), 256, 0, stream>>>(
            hb, Wt, bl + (size_t)l * HC, br + (size_t)l * HC, xlb, xrb);
        float* hout = (l == 0) ? h_mid : (float*)d_out;
        k_node<<<NN / 4, 256, 0, stream>>>(xlb, xrb, wep, csr, rowptr,
                                           att + (size_t)l * HH * CC,
                                           bias_o + (size_t)l * DM,
                                           ln_g + (size_t)l * DM,
                                           ln_b + (size_t)l * DM,
                                           h, hout, hb);
        h = hout;
    }
}

// Round 3
// 462.054 us; speedup vs baseline: 1.6672x; 1.0182x over previous
//
#include <hip/hip_runtime.h>
#include <hip/hip_bf16.h>
#include <math.h>

#define NN 32768
#define EE 262144
#define DM 128
#define HH 4
#define CC 128
#define HC 512
#define RD 64
#define NRELS 64
#define LEAKS 0.2f
#define LNEPS 1e-5f

typedef __hip_bfloat16 bf16;
typedef __attribute__((ext_vector_type(8))) short short8;
typedef __attribute__((ext_vector_type(4))) float f32x4;

__device__ __forceinline__ void unpack8(uint4 u, float* f) {
    f[0] = __uint_as_float((u.x & 0xffffu) << 16);
    f[1] = __uint_as_float(u.x & 0xffff0000u);
    f[2] = __uint_as_float((u.y & 0xffffu) << 16);
    f[3] = __uint_as_float(u.y & 0xffff0000u);
    f[4] = __uint_as_float((u.z & 0xffffu) << 16);
    f[5] = __uint_as_float(u.z & 0xffff0000u);
    f[6] = __uint_as_float((u.w & 0xffffu) << 16);
    f[7] = __uint_as_float(u.w & 0xffff0000u);
}

// ---------------- CSR build ----------------
__global__ void k_deg(const int* __restrict__ dst, int* __restrict__ deg) {
    int e = blockIdx.x * 256 + threadIdx.x;
    if (e < EE) atomicAdd(&deg[dst[e]], 1);
}

// hierarchical exclusive scan of deg[NN] -> rowptr
__global__ void k_scan1(const int* __restrict__ deg, int* __restrict__ rowptr,
                        int* __restrict__ bsum) {
    __shared__ int s[256];
    int b = blockIdx.x, t = threadIdx.x;
    int v = deg[b * 256 + t];
    s[t] = v;
    __syncthreads();
    for (int off = 1; off < 256; off <<= 1) {
        int x = (t >= off) ? s[t - off] : 0;
        __syncthreads();
        s[t] += x;
        __syncthreads();
    }
    rowptr[b * 256 + t] = s[t] - v;  // exclusive within block
    if (t == 255) bsum[b] = s[255];
}

__global__ void k_scan2(const int* __restrict__ bsum, int* __restrict__ boff) {
    __shared__ int s[128];
    int t = threadIdx.x;
    int v = bsum[t];
    s[t] = v;
    __syncthreads();
    for (int off = 1; off < 128; off <<= 1) {
        int x = (t >= off) ? s[t - off] : 0;
        __syncthreads();
        s[t] += x;
        __syncthreads();
    }
    boff[t] = s[t] - v;
    if (t == 127) boff[128] = s[127];
}

__global__ void k_scan3(int* __restrict__ rowptr, const int* __restrict__ boff) {
    int i = blockIdx.x * 256 + threadIdx.x;
    rowptr[i] += boff[i >> 8];
    if (i == NN - 1) rowptr[NN] = boff[128];
}

__global__ void k_fill(const int* __restrict__ src, const int* __restrict__ dst,
                       const int* __restrict__ etype, const int* __restrict__ rowptr,
                       int* __restrict__ cursor, unsigned* __restrict__ csr) {
    int e = blockIdx.x * 256 + threadIdx.x;
    if (e < EE) {
        int d = dst[e];
        int pos = atomicAdd(&cursor[d], 1);
        csr[rowptr[d] + pos] = (unsigned)src[e] | ((unsigned)etype[e] << 16);
    }
}

// ---------------- h f32 -> bf16 cast ----------------
__global__ void k_cast(const float* __restrict__ x, bf16* __restrict__ hb) {
    int i = blockIdx.x * 256 + threadIdx.x;
    const float4* p = (const float4*)x;
    float4 f0 = p[i * 2], f1 = p[i * 2 + 1];
    bf16 o[8];
    o[0] = __float2bfloat16(f0.x); o[1] = __float2bfloat16(f0.y);
    o[2] = __float2bfloat16(f0.z); o[3] = __float2bfloat16(f0.w);
    o[4] = __float2bfloat16(f1.x); o[5] = __float2bfloat16(f1.y);
    o[6] = __float2bfloat16(f1.z); o[7] = __float2bfloat16(f1.w);
    *reinterpret_cast<uint4*>(hb + (size_t)i * 8) = *reinterpret_cast<uint4*>(o);
}

// ---------------- Wt[l] = [Wl|Wr]^T  bf16 [2][1024][128], both layers ----------------
__global__ void k_repack2(const float* __restrict__ Wl, const float* __restrict__ Wr,
                          bf16* __restrict__ Wt) {
    int idx = blockIdx.x * 256 + threadIdx.x;  // 262144 total
    int l = idx >> 17;
    int rem = idx & 131071;
    int k = rem >> 10;
    int c = rem & 1023;
    const float* WlL = Wl + (size_t)l * DM * HC;
    const float* WrL = Wr + (size_t)l * DM * HC;
    float v = (c < HC) ? WlL[k * HC + c] : WrL[k * HC + (c - HC)];
    Wt[(size_t)l * 1024 * DM + (size_t)c * DM + k] = __float2bfloat16(v);
}

// ---------------- wep[l] = rel_emb @ We[l], bf16 [2][64][512] ----------------
__global__ void k_wep2(const float* __restrict__ rel_emb, const float* __restrict__ We,
                       bf16* __restrict__ wep) {
    int l = blockIdx.x >> 6;
    int r = blockIdx.x & 63;
    int c = threadIdx.x;
    const float* WeL = We + (size_t)l * RD * HC;
    __shared__ float a[RD];
    if (c < RD) a[c] = rel_emb[r * RD + c];
    __syncthreads();
    float s = 0.f;
#pragma unroll 8
    for (int k = 0; k < RD; ++k) s += a[k] * WeL[k * HC + c];
    wep[(size_t)l * NRELS * HC + (size_t)r * HC + c] = __float2bfloat16(s);
}

// ---------------- MFMA GEMM: [xl|xr] = hb @ Wt^T + bias ----------------
__global__ __launch_bounds__(256) void k_gemm_mfma(
    const bf16* __restrict__ hb, const bf16* __restrict__ Wt,
    const float* __restrict__ bl, const float* __restrict__ br,
    bf16* __restrict__ xlb, bf16* __restrict__ xrb) {
    int lane = threadIdx.x & 63;
    int wave = threadIdx.x >> 6;
    int rbase = blockIdx.x * 32;
    int cbase = blockIdx.y * 256 + wave * 64;
    int lr = lane & 15;
    int lk = lane >> 4;
    const short* ha = (const short*)hb;
    const short* wa = (const short*)Wt;

    short8 a[2][4], b[4][4];
#pragma unroll
    for (int mi = 0; mi < 2; ++mi)
#pragma unroll
        for (int kk = 0; kk < 4; ++kk)
            a[mi][kk] = *(const short8*)(ha + (size_t)(rbase + mi * 16 + lr) * DM + kk * 32 + lk * 8);
#pragma unroll
    for (int ni = 0; ni < 4; ++ni)
#pragma unroll
        for (int kk = 0; kk < 4; ++kk)
            b[ni][kk] = *(const short8*)(wa + (size_t)(cbase + ni * 16 + lr) * DM + kk * 32 + lk * 8);

    f32x4 c[2][4];
#pragma unroll
    for (int mi = 0; mi < 2; ++mi)
#pragma unroll
        for (int ni = 0; ni < 4; ++ni)
            c[mi][ni] = (f32x4){0.f, 0.f, 0.f, 0.f};

#pragma unroll
    for (int kk = 0; kk < 4; ++kk)
#pragma unroll
        for (int mi = 0; mi < 2; ++mi)
#pragma unroll
            for (int ni = 0; ni < 4; ++ni)
                c[mi][ni] = __builtin_amdgcn_mfma_f32_16x16x32_bf16(
                    a[mi][kk], b[ni][kk], c[mi][ni], 0, 0, 0);

#pragma unroll
    for (int ni = 0; ni < 4; ++ni) {
        int col = cbase + ni * 16 + lr;
        float bv = (col < HC) ? bl[col] : br[col - HC];
        bf16* outp;
        int cc;
        if (col < HC) { outp = xlb; cc = col; } else { outp = xrb; cc = col - HC; }
#pragma unroll
        for (int mi = 0; mi < 2; ++mi) {
#pragma unroll
            for (int r = 0; r < 4; ++r) {
                int row = rbase + mi * 16 + lk * 4 + r;
                outp[(size_t)row * HC + cc] = __float2bfloat16(c[mi][ni][r] + bv);
            }
        }
    }
}

// ---------------- fused per-node: edge loop (online softmax + wep-mean) +
//                  self-loop + head-mean + bias + GELU + residual + LN ----------------
__global__ __launch_bounds__(1024, 8) void k_node(
    const bf16* __restrict__ xlb, const bf16* __restrict__ xrb,
    const bf16* __restrict__ wep,
    const unsigned* __restrict__ csr, const int* __restrict__ rowptr,
    const float* __restrict__ attL, const float* __restrict__ biasL,
    const float* __restrict__ lngL, const float* __restrict__ lnbL,
    const float* __restrict__ h_in, float* __restrict__ h_out,
    bf16* __restrict__ hb_out) {
    __shared__ short wepS[NRELS * HC];  // 64 KB, 2 blocks/CU
    int tid = threadIdx.x;
    {
        const uint4* ws = (const uint4*)wep;
        uint4* wd = (uint4*)wepS;
#pragma unroll
        for (int i = 0; i < 4; ++i) wd[tid + i * 1024] = ws[tid + i * 1024];
    }
    __syncthreads();

    int lane = tid & 63;
    int wave = tid >> 6;
    int n = blockIdx.x * 16 + wave;
    int head = lane >> 4;
    const int g0 = lane * 8;          // global channel in [0,512)
    const int ch0 = (lane & 15) * 8;  // channel within head, [0,128)
    const short* xla = (const short*)xlb;

    float attv[8];
#pragma unroll
    for (int j = 0; j < 8; ++j) attv[j] = attL[head * CC + ch0 + j];

    float xrn[8], xln[8];
    unpack8(*(const uint4*)((const short*)xrb + (size_t)n * HC + g0), xrn);
    unpack8(*(const uint4*)(xla + (size_t)n * HC + g0), xln);

    float m = -1e30f;
    float denom = 0.f;
    float acc[8], wpsum[8];
#pragma unroll
    for (int j = 0; j < 8; ++j) { acc[j] = 0.f; wpsum[j] = 0.f; }

    int r0 = rowptr[n], r1 = rowptr[n + 1];
    int d = r1 - r0;
    if (d > 0) {
        unsigned u = csr[r0];
        uint4 xv = *(const uint4*)(xla + (size_t)(u & 0xffffu) * HC + g0);
        for (int i = r0; i < r1; ++i) {
            int inx = (i + 1 < r1) ? (i + 1) : i;
            unsigned un = csr[inx];                                         // prefetch idx
            uint4 xn = *(const uint4*)(xla + (size_t)(un & 0xffffu) * HC + g0);  // prefetch row
            uint4 wv = *(const uint4*)(wepS + (u >> 16) * HC + g0);         // LDS, uniform row
            float xs[8], wp[8];
            unpack8(xv, xs);
            unpack8(wv, wp);
            float p2 = 0.f;
#pragma unroll
            for (int j = 0; j < 8; ++j) {
                wpsum[j] += wp[j];
                float v = xs[j] + xrn[j] + wp[j];
                v = (v > 0.f) ? v : LEAKS * v;
                p2 += v * attv[j];
            }
            p2 += __shfl_xor(p2, 1);
            p2 += __shfl_xor(p2, 2);
            p2 += __shfl_xor(p2, 4);
            p2 += __shfl_xor(p2, 8);
            float mnew = fmaxf(m, p2);
            float scale = __expf(m - mnew);
            float p = __expf(p2 - mnew);
            denom = denom * scale + p;
#pragma unroll
            for (int j = 0; j < 8; ++j) acc[j] = acc[j] * scale + p * xs[j];
            m = mnew;
            u = un;
            xv = xn;
        }
    }

    // self-loop: ep_self = mean of incoming wep rows (linearity of @We)
    float invd = (d > 0) ? (1.0f / (float)d) : 1.0f;
    float p2 = 0.f;
#pragma unroll
    for (int j = 0; j < 8; ++j) {
        float v = xln[j] + xrn[j] + wpsum[j] * invd;
        v = (v > 0.f) ? v : LEAKS * v;
        p2 += v * attv[j];
    }
    p2 += __shfl_xor(p2, 1);
    p2 += __shfl_xor(p2, 2);
    p2 += __shfl_xor(p2, 4);
    p2 += __shfl_xor(p2, 8);
    {
        float mnew = fmaxf(m, p2);
        float scale = __expf(m - mnew);
        float p = __expf(p2 - mnew);
        denom = denom * scale + p;
#pragma unroll
        for (int j = 0; j < 8; ++j) acc[j] = acc[j] * scale + p * xln[j];
    }

    // alpha normalize + mean over heads + GELU + residual + LN
    float inv = 1.0f / (denom + 1e-16f);
    const float4* hp = (const float4*)(h_in + (size_t)n * DM + ch0);
    float4 h0 = hp[0], h1 = hp[1];
    float hin[8] = {h0.x, h0.y, h0.z, h0.w, h1.x, h1.y, h1.z, h1.w};
    float hn[8];
    float lsum = 0.f, lsq = 0.f;
#pragma unroll
    for (int j = 0; j < 8; ++j) {
        float v = acc[j] * inv;
        v += __shfl_xor(v, 16);
        v += __shfl_xor(v, 32);
        float x = v * 0.25f + biasL[ch0 + j];
        float ge = 0.5f * x * (1.0f + erff(x * 0.70710678f));
        float hv = hin[j] + ge;
        hn[j] = hv;
        lsum += hv;
        lsq += hv * hv;
    }
    lsum += __shfl_xor(lsum, 1);
    lsum += __shfl_xor(lsum, 2);
    lsum += __shfl_xor(lsum, 4);
    lsum += __shfl_xor(lsum, 8);
    lsq += __shfl_xor(lsq, 1);
    lsq += __shfl_xor(lsq, 2);
    lsq += __shfl_xor(lsq, 4);
    lsq += __shfl_xor(lsq, 8);
    float mu = lsum * (1.0f / 128.f);
    float var = lsq * (1.0f / 128.f) - mu * mu;
    float rstd = rsqrtf(var + LNEPS);
    if (lane < 16) {
#pragma unroll
        for (int j = 0; j < 8; ++j) {
            float o = (hn[j] - mu) * rstd * lngL[ch0 + j] + lnbL[ch0 + j];
            h_out[(size_t)n * DM + ch0 + j] = o;
            hb_out[(size_t)n * DM + ch0 + j] = __float2bfloat16(o);
        }
    }
}

extern "C" void kernel_launch(void* const* d_in, const int* in_sizes, int n_in,
                              void* d_out, int out_size, void* d_ws, size_t ws_size,
                              hipStream_t stream) {
    const float* x_flat   = (const float*)d_in[0];
    const int*   edge_idx = (const int*)d_in[1];
    const int*   edge_typ = (const int*)d_in[2];
    // d_in[3]: valid_mask_flat — all-true; where() is identity.
    const float* rel_emb  = (const float*)d_in[4];
    const float* Wl       = (const float*)d_in[5];
    const float* bl       = (const float*)d_in[6];
    const float* Wr       = (const float*)d_in[7];
    const float* br       = (const float*)d_in[8];
    const float* We       = (const float*)d_in[9];
    const float* att      = (const float*)d_in[10];
    const float* bias_o   = (const float*)d_in[11];
    const float* ln_g     = (const float*)d_in[12];
    const float* ln_b     = (const float*)d_in[13];

    const int* srcp = edge_idx;
    const int* dstp = edge_idx + EE;

    char* w = (char*)d_ws;
    auto alloc = [&](size_t bytes) -> void* {
        void* p = (void*)w;
        w += (bytes + 255) & ~(size_t)255;
        return p;
    };
    bf16*  xlb    = (bf16*)alloc((size_t)NN * HC * 2);
    bf16*  xrb    = (bf16*)alloc((size_t)NN * HC * 2);
    bf16*  hb     = (bf16*)alloc((size_t)NN * DM * 2);
    float* h_mid  = (float*)alloc((size_t)NN * DM * 4);
    bf16*  wep    = (bf16*)alloc((size_t)2 * NRELS * HC * 2);
    bf16*  Wt     = (bf16*)alloc((size_t)2 * 1024 * DM * 2);
    int*   deg    = (int*)alloc((size_t)NN * 4);
    int*   rowptr = (int*)alloc((size_t)(NN + 1) * 4);
    int*   cursor = (int*)alloc((size_t)NN * 4);
    int*   bsum   = (int*)alloc((size_t)128 * 4);
    int*   boff   = (int*)alloc((size_t)129 * 4);
    unsigned* csr = (unsigned*)alloc((size_t)EE * 4);

    hipMemsetAsync(deg, 0, (size_t)NN * 4, stream);
    hipMemsetAsync(cursor, 0, (size_t)NN * 4, stream);

    k_deg<<<EE / 256, 256, 0, stream>>>(dstp, deg);
    k_scan1<<<NN / 256, 256, 0, stream>>>(deg, rowptr, bsum);
    k_scan2<<<1, 128, 0, stream>>>(bsum, boff);
    k_scan3<<<NN / 256, 256, 0, stream>>>(rowptr, boff);
    k_fill<<<EE / 256, 256, 0, stream>>>(srcp, dstp, edge_typ, rowptr, cursor, csr);
    k_cast<<<NN * DM / 8 / 256, 256, 0, stream>>>(x_flat, hb);
    k_wep2<<<128, 512, 0, stream>>>(rel_emb, We, wep);
    k_repack2<<<1024, 256, 0, stream>>>(Wl, Wr, Wt);

    const float* h = x_flat;
    for (int l = 0; l < 2; ++l) {
        k_gemm_mfma<<<dim3(NN / 32, 4), 256, 0, stream>>>(
            hb, Wt + (size_t)l * 1024 * DM,
            bl + (size_t)l * HC, br + (size_t)l * HC, xlb, xrb);
        float* hout = (l == 0) ? h_mid : (float*)d_out;
        k_node<<<NN / 16, 1024, 0, stream>>>(xlb, xrb, wep + (size_t)l * NRELS * HC,
                                             csr, rowptr,
                                             att + (size_t)l * HH * CC,
                                             bias_o + (size_t)l * DM,
                                             ln_g + (size_t)l * DM,
                                             ln_b + (size_t)l * DM,
                                             h, hout, hb);
        h = hout;
    }
}